// Round 1
// 995.879 us; speedup vs baseline: 1.0147x; 1.0147x over previous
//
#include <hip/hip_runtime.h>

// AttentionFusion on MI355X (gfx950). B=32, C=1024, HW=1024.
// All GEMMs 1024^3, bf16 MFMA fp32-acc.
// This revision: 256x256 tile, BK=64, 512 threads (8 waves, 2Mx4N),
// 4-phase K-step with counted vmcnt (T3+T4), setprio around MFMA (T5),
// raw s_barrier (no __syncthreads -> no vmcnt(0) drain), XOR-swizzled LDS
// (T2, measured 0 bank conflicts in previous revision).

typedef __bf16 bf16x8 __attribute__((ext_vector_type(8)));
typedef float floatx4 __attribute__((ext_vector_type(4)));

__device__ __forceinline__ unsigned short f2bf(float f) {
  union { float f; unsigned int u; } c; c.f = f;
  unsigned int u = c.u;
  u += 0x7fffu + ((u >> 16) & 1u);   // RNE to bf16
  return (unsigned short)(u >> 16);
}

__device__ __forceinline__ float tanh_fast(float x) {
  x = fminf(15.0f, fmaxf(-15.0f, x));
  float t = __expf(2.0f * x);
  return (t - 1.0f) / (t + 1.0f);
}

__device__ __forceinline__ void stage16(unsigned short* dst,
                                        const unsigned short* src) {
  __builtin_amdgcn_global_load_lds(
      (__attribute__((address_space(1))) void*)src,
      (__attribute__((address_space(3))) void*)dst, 16, 0, 0);
}

// ---------------------------------------------------------------------------
// 256x256 GEMM core: acc[m][n] += sum_k A[m][k]*B[n][k], K=1024, BK=64.
//
// LDS per operand per buffer: 256 rows x 64 cols bf16 = 32 KiB, row = 128 B,
// column-group cg (8 elems = 16 B) stored at phys slot cg ^ (row&7).
// Staged in 4 "units" of 64 rows; unit u, thread t (512 threads) writes LDS
// bytes u*8192 + t*16 <- global row (u*64 + t/8), col-group (t&7)^((t/8)&7).
// Readers XOR the same term -> conflict-free (measured 0 conflicts).
//
// Per K-tile (4 phases, 16 MFMA each):
//   P0: read B full (8 ds_read_b128) + A rows [0,32) (4); stage next B units 0,1
//   P1: read A rows [32,64);                              stage next B units 2,3
//       -> s_waitcnt vmcnt(4): retires PREV tile's A units 1,3 (read in P2/P3)
//   P2: read A rows [64,96)  (units 1,3);                 stage next A units 0,2
//   P3: read A rows [96,128) (units 1,3);                 stage next A units 1,3
//       -> s_waitcnt vmcnt(2): retires next tile's B0-3 + A0,2 (read in P0/P1)
// Every wait leaves >=2 stage-loads in flight (counted, never 0 mid-loop).
// All stage-writes target the buffer NOT being read this tile; slot reuse is
// separated from last read by a "memory"-clobbered waitcnt + s_barrier.
// ---------------------------------------------------------------------------
__device__ __forceinline__ void gemm256_core(
    const unsigned short* __restrict__ Ab,
    const unsigned short* __restrict__ Bb,
    int m0, int n0,
    unsigned short* lA, unsigned short* lB,
    floatx4 acc[8][4])
{
  constexpr int K  = 1024;
  constexpr int NT = 16;
  const int tid  = threadIdx.x;
  const int w    = tid >> 6;
  const int lane = tid & 63;
  const int quad = lane >> 4;
  const int lm   = lane & 15;
  const int wm   = (w >> 2) * 128;   // wave m-origin within tile
  const int wn   = (w & 3) * 64;     // wave n-origin within tile
  const int xr   = lm & 7;

  const int srow = tid >> 3;                       // 0..63 row within unit
  const int scg  = (lane & 7) ^ ((lane >> 3) & 7); // pre-swizzled source cg
  const unsigned short* gA = Ab + (size_t)(m0 + srow) * K + scg * 8;
  const unsigned short* gB = Bb + (size_t)(n0 + srow) * K + scg * 8;
  unsigned short* const dA = lA + w * 512;  // wave-uniform LDS stage base
  unsigned short* const dB = lB + w * 512;

  // prologue: stage K-tile 0 into buffer 0, drain once (allowed outside loop)
#pragma unroll
  for (int u = 0; u < 4; ++u) stage16(dA + u * 4096, gA + (size_t)(u * 64) * K);
#pragma unroll
  for (int u = 0; u < 4; ++u) stage16(dB + u * 4096, gB + (size_t)(u * 64) * K);
  asm volatile("s_waitcnt vmcnt(0)" ::: "memory");
  __builtin_amdgcn_s_barrier();

  for (int kt = 0; kt < NT; ++kt) {
    const int cb  = (kt & 1) * 16384;  // current buffer (ushort offset)
    const int nxb = 16384 - cb;        // next buffer
    const unsigned short* cA = lA + cb;
    const unsigned short* cB = lB + cb;
    const int k1 = (kt + 1) << 6;
    const bool st = (kt + 1) < NT;

    bf16x8 bfr[4][2];   // B fragments live for the whole tile (32 VGPR)

    // ---------------- Phase 0 ----------------
    {
      bf16x8 afr[2][2];
#pragma unroll
      for (int j = 0; j < 4; ++j)
#pragma unroll
        for (int kf = 0; kf < 2; ++kf)
          bfr[j][kf] = *(const bf16x8*)(cB + (wn + 16 * j + lm) * 64 +
                                        (((kf * 4 + quad) ^ xr) * 8));
#pragma unroll
      for (int i2 = 0; i2 < 2; ++i2)
#pragma unroll
        for (int kf = 0; kf < 2; ++kf)
          afr[i2][kf] = *(const bf16x8*)(cA + (wm + 16 * i2 + lm) * 64 +
                                         (((kf * 4 + quad) ^ xr) * 8));
      if (st) {
        stage16(dB + nxb + 0 * 4096, gB + (size_t)(0 * 64) * K + k1);
        stage16(dB + nxb + 1 * 4096, gB + (size_t)(1 * 64) * K + k1);
      }
      __builtin_amdgcn_s_barrier();
      asm volatile("s_waitcnt lgkmcnt(0)" ::: "memory");
      __builtin_amdgcn_s_setprio(1);
#pragma unroll
      for (int i2 = 0; i2 < 2; ++i2)
#pragma unroll
        for (int j = 0; j < 4; ++j)
#pragma unroll
          for (int kf = 0; kf < 2; ++kf)
            acc[i2][j] = __builtin_amdgcn_mfma_f32_16x16x32_bf16(
                afr[i2][kf], bfr[j][kf], acc[i2][j], 0, 0, 0);
      __builtin_amdgcn_s_setprio(0);
      __builtin_amdgcn_s_barrier();
    }

    // ---------------- Phase 1 ----------------
    {
      bf16x8 afr[2][2];
#pragma unroll
      for (int i2 = 0; i2 < 2; ++i2)
#pragma unroll
        for (int kf = 0; kf < 2; ++kf)
          afr[i2][kf] = *(const bf16x8*)(cA + (wm + 32 + 16 * i2 + lm) * 64 +
                                         (((kf * 4 + quad) ^ xr) * 8));
      if (st) {
        stage16(dB + nxb + 2 * 4096, gB + (size_t)(2 * 64) * K + k1);
        stage16(dB + nxb + 3 * 4096, gB + (size_t)(3 * 64) * K + k1);
      }
      __builtin_amdgcn_s_barrier();
      asm volatile("s_waitcnt lgkmcnt(0)" ::: "memory");
      __builtin_amdgcn_s_setprio(1);
#pragma unroll
      for (int i2 = 0; i2 < 2; ++i2)
#pragma unroll
        for (int j = 0; j < 4; ++j)
#pragma unroll
          for (int kf = 0; kf < 2; ++kf)
            acc[2 + i2][j] = __builtin_amdgcn_mfma_f32_16x16x32_bf16(
                afr[i2][kf], bfr[j][kf], acc[2 + i2][j], 0, 0, 0);
      __builtin_amdgcn_s_setprio(0);
      // retire prev tile's A units 1,3 (needed by P2); leave this tile's
      // 4 stage-loads (P0,P1) in flight.
      if (st) asm volatile("s_waitcnt vmcnt(4)" ::: "memory");
      else    asm volatile("s_waitcnt vmcnt(0)" ::: "memory");
      __builtin_amdgcn_s_barrier();
    }

    // ---------------- Phase 2 ----------------
    {
      bf16x8 afr[2][2];
#pragma unroll
      for (int i2 = 0; i2 < 2; ++i2)
#pragma unroll
        for (int kf = 0; kf < 2; ++kf)
          afr[i2][kf] = *(const bf16x8*)(cA + (wm + 64 + 16 * i2 + lm) * 64 +
                                         (((kf * 4 + quad) ^ xr) * 8));
      if (st) {
        stage16(dA + nxb + 0 * 4096, gA + (size_t)(0 * 64) * K + k1);
        stage16(dA + nxb + 2 * 4096, gA + (size_t)(2 * 64) * K + k1);
      }
      __builtin_amdgcn_s_barrier();
      asm volatile("s_waitcnt lgkmcnt(0)" ::: "memory");
      __builtin_amdgcn_s_setprio(1);
#pragma unroll
      for (int i2 = 0; i2 < 2; ++i2)
#pragma unroll
        for (int j = 0; j < 4; ++j)
#pragma unroll
          for (int kf = 0; kf < 2; ++kf)
            acc[4 + i2][j] = __builtin_amdgcn_mfma_f32_16x16x32_bf16(
                afr[i2][kf], bfr[j][kf], acc[4 + i2][j], 0, 0, 0);
      __builtin_amdgcn_s_setprio(0);
      __builtin_amdgcn_s_barrier();
    }

    // ---------------- Phase 3 ----------------
    {
      bf16x8 afr[2][2];
#pragma unroll
      for (int i2 = 0; i2 < 2; ++i2)
#pragma unroll
        for (int kf = 0; kf < 2; ++kf)
          afr[i2][kf] = *(const bf16x8*)(cA + (wm + 96 + 16 * i2 + lm) * 64 +
                                         (((kf * 4 + quad) ^ xr) * 8));
      if (st) {
        stage16(dA + nxb + 1 * 4096, gA + (size_t)(1 * 64) * K + k1);
        stage16(dA + nxb + 3 * 4096, gA + (size_t)(3 * 64) * K + k1);
      }
      __builtin_amdgcn_s_barrier();
      asm volatile("s_waitcnt lgkmcnt(0)" ::: "memory");
      __builtin_amdgcn_s_setprio(1);
#pragma unroll
      for (int i2 = 0; i2 < 2; ++i2)
#pragma unroll
        for (int j = 0; j < 4; ++j)
#pragma unroll
          for (int kf = 0; kf < 2; ++kf)
            acc[6 + i2][j] = __builtin_amdgcn_mfma_f32_16x16x32_bf16(
                afr[i2][kf], bfr[j][kf], acc[6 + i2][j], 0, 0, 0);
      __builtin_amdgcn_s_setprio(0);
      // retire next tile's B units 0-3 + A units 0,2 (read in next P0/P1);
      // leave this tile's P3 stage-loads (A units 1,3) in flight.
      if (st) asm volatile("s_waitcnt vmcnt(2)" ::: "memory");
      else    asm volatile("s_waitcnt vmcnt(0)" ::: "memory");
      __builtin_amdgcn_s_barrier();
    }
  }
}

// ---------------------------------------------------------------------------
// Generic epilogue GEMM (templated): C = epi(scale * A.B^T)
// ---------------------------------------------------------------------------
template<int OUT_F32, int BIAS_MODE /*0 none,1 m,2 n*/, int TANH_ON, int RESID_ON>
__global__ __launch_bounds__(512, 2)
void gemm_bt(const unsigned short* __restrict__ A,
             const unsigned short* __restrict__ B,
             void* __restrict__ Cv,
             const float* __restrict__ bias,
             const float* __restrict__ resid,
             float scale,
             size_t sA, size_t sB, size_t sC, size_t sR)
{
  __shared__ unsigned short lA[2 * 16384];   // 64 KiB
  __shared__ unsigned short lB[2 * 16384];   // 64 KiB
  const int m0 = blockIdx.y * 256, n0 = blockIdx.x * 256;
  const int lane = threadIdx.x & 63, w = threadIdx.x >> 6;
  const int quad = lane >> 4, lm = lane & 15;
  const int wm = (w >> 2) * 128, wn = (w & 3) * 64;

  floatx4 acc[8][4];
#pragma unroll
  for (int i = 0; i < 8; ++i)
#pragma unroll
    for (int j = 0; j < 4; ++j) acc[i][j] = (floatx4)(0.0f);

  gemm256_core(A + blockIdx.z * sA, B + blockIdx.z * sB, m0, n0, lA, lB, acc);

  float* Cf = (float*)Cv + blockIdx.z * sC;
  unsigned short* Cb = (unsigned short*)Cv + blockIdx.z * sC;
  const float* rp = RESID_ON ? (resid + blockIdx.z * sR) : (const float*)0;

  // C/D mapping (verified): n = lane&15, m = quad*4 + reg
#pragma unroll
  for (int i = 0; i < 8; ++i) {
    const int mbase = m0 + wm + 16 * i + quad * 4;
#pragma unroll
    for (int j = 0; j < 4; ++j) {
      const int n = n0 + wn + 16 * j + lm;
#pragma unroll
      for (int r = 0; r < 4; ++r) {
        const int m = mbase + r;
        float val = acc[i][j][r] * scale;
        if (BIAS_MODE == 1) val += bias[m];
        if (BIAS_MODE == 2) val += bias[n];
        if (TANH_ON) val = tanh_fast(val);
        if (RESID_ON) val += rp[(size_t)m * 1024 + n];
        if (OUT_F32) Cf[(size_t)m * 1024 + n] = val;
        else         Cb[(size_t)m * 1024 + n] = f2bf(val);
      }
    }
  }
}

// ---------------------------------------------------------------------------
// Fused Q/K/V GEMM: z in [0,3*nb) selects op + batch.  All tanh, bf16 out.
// ---------------------------------------------------------------------------
__global__ __launch_bounds__(512, 2)
void qkv_gemm(const unsigned short* __restrict__ wqb,
              const unsigned short* __restrict__ wkb,
              const unsigned short* __restrict__ wvb,
              const unsigned short* __restrict__ Xt,
              const unsigned short* __restrict__ Yt,
              unsigned short* __restrict__ Qb,
              unsigned short* __restrict__ Kb,
              unsigned short* __restrict__ Vt,
              const float* __restrict__ bq,
              const float* __restrict__ bk,
              const float* __restrict__ bv,
              size_t sBf, int nb)
{
  __shared__ unsigned short lA[2 * 16384];
  __shared__ unsigned short lB[2 * 16384];
  const int z = blockIdx.z;
  int op, b;
  if (z >= 2 * nb)      { op = 2; b = z - 2 * nb; }
  else if (z >= nb)     { op = 1; b = z - nb; }
  else                  { op = 0; b = z; }

  const unsigned short *A, *B;
  unsigned short* C;
  const float* bias;
  int biasM;   // 1 = along m, 0 = along n
  if (op == 0)      { A = wqb;            B = Xt + b * sBf; C = Qb + b * sBf; bias = bq; biasM = 1; }
  else if (op == 1) { A = wkb;            B = Yt + b * sBf; C = Kb + b * sBf; bias = bk; biasM = 1; }
  else              { A = Yt + b * sBf;   B = wvb;          C = Vt + b * sBf; bias = bv; biasM = 0; }

  const int m0 = blockIdx.y * 256, n0 = blockIdx.x * 256;
  const int lane = threadIdx.x & 63, w = threadIdx.x >> 6;
  const int quad = lane >> 4, lm = lane & 15;
  const int wm = (w >> 2) * 128, wn = (w & 3) * 64;

  floatx4 acc[8][4];
#pragma unroll
  for (int i = 0; i < 8; ++i)
#pragma unroll
    for (int j = 0; j < 4; ++j) acc[i][j] = (floatx4)(0.0f);

  gemm256_core(A, B, m0, n0, lA, lB, acc);

#pragma unroll
  for (int i = 0; i < 8; ++i) {
    const int mbase = m0 + wm + 16 * i + quad * 4;
#pragma unroll
    for (int j = 0; j < 4; ++j) {
      const int n = n0 + wn + 16 * j + lm;
      const float bn = biasM ? 0.0f : bias[n];
#pragma unroll
      for (int r = 0; r < 4; ++r) {
        const int m = mbase + r;
        float val = acc[i][j][r] + (biasM ? bias[m] : bn);
        val = tanh_fast(val);
        C[(size_t)m * 1024 + n] = f2bf(val);
      }
    }
  }
}

// ---------------------------------------------------------------------------
// Dual transpose 1024x1024 fp32 -> bf16: z<nb: in0->out0, else in1->out1
// ---------------------------------------------------------------------------
__global__ __launch_bounds__(256)
void transpose2(const float* __restrict__ in0, const float* __restrict__ in1,
                unsigned short* __restrict__ out0, unsigned short* __restrict__ out1,
                size_t sIn, size_t sOut, int nb)
{
  __shared__ float tile[32][33];
  const int z = blockIdx.z;
  const float* in;
  unsigned short* out;
  if (z < nb) { in = in0 + (size_t)z * sIn;        out = out0 + (size_t)z * sOut; }
  else        { in = in1 + (size_t)(z - nb) * sIn; out = out1 + (size_t)(z - nb) * sOut; }

  const int x  = blockIdx.x * 32 + threadIdx.x;
  const int y0 = blockIdx.y * 32;
#pragma unroll
  for (int k = 0; k < 32; k += 8)
    tile[threadIdx.y + k][threadIdx.x] =
        in[(size_t)(y0 + threadIdx.y + k) * 1024 + x];
  __syncthreads();
  const int xo  = blockIdx.y * 32 + threadIdx.x;
  const int yo0 = blockIdx.x * 32;
#pragma unroll
  for (int k = 0; k < 32; k += 8)
    out[(size_t)(yo0 + threadIdx.y + k) * 1024 + xo] =
        f2bf(tile[threadIdx.x][threadIdx.y + k]);
}

// ---------------------------------------------------------------------------
// Row softmax: 1024 fp32 -> 1024 bf16, one block per row
// ---------------------------------------------------------------------------
__global__ __launch_bounds__(256)
void softmax_rows(const float* __restrict__ S, unsigned short* __restrict__ W,
                  size_t sS, size_t sW)
{
  const float* s = S + blockIdx.y * sS + (size_t)blockIdx.x * 1024;
  unsigned short* w = W + blockIdx.y * sW + (size_t)blockIdx.x * 1024;
  const int t = threadIdx.x;
  float4 v = ((const float4*)s)[t];
  float mx = fmaxf(fmaxf(v.x, v.y), fmaxf(v.z, v.w));
#pragma unroll
  for (int off = 32; off > 0; off >>= 1)
    mx = fmaxf(mx, __shfl_xor(mx, off));
  __shared__ float redm[4], reds[4];
  const int lane = t & 63, wv = t >> 6;
  if (lane == 0) redm[wv] = mx;
  __syncthreads();
  mx = fmaxf(fmaxf(redm[0], redm[1]), fmaxf(redm[2], redm[3]));
  float e0 = __expf(v.x - mx), e1 = __expf(v.y - mx),
        e2 = __expf(v.z - mx), e3 = __expf(v.w - mx);
  float sum = e0 + e1 + e2 + e3;
#pragma unroll
  for (int off = 32; off > 0; off >>= 1)
    sum += __shfl_xor(sum, off);
  if (lane == 0) reds[wv] = sum;
  __syncthreads();
  sum = reds[0] + reds[1] + reds[2] + reds[3];
  const float inv = 1.0f / sum;
  w[4 * t + 0] = f2bf(e0 * inv);
  w[4 * t + 1] = f2bf(e1 * inv);
  w[4 * t + 2] = f2bf(e2 * inv);
  w[4 * t + 3] = f2bf(e3 * inv);
}

// ---------------------------------------------------------------------------
// Convert all four 1024x1024 fp32 weights -> bf16 in one dispatch (y=op)
// ---------------------------------------------------------------------------
__global__ __launch_bounds__(256)
void cvt_all(const float* __restrict__ s0, const float* __restrict__ s1,
             const float* __restrict__ s2, const float* __restrict__ s3,
             unsigned short* __restrict__ d0, unsigned short* __restrict__ d1,
             unsigned short* __restrict__ d2, unsigned short* __restrict__ d3)
{
  const float* in; unsigned short* out;
  switch (blockIdx.y) {
    case 0: in = s0; out = d0; break;
    case 1: in = s1; out = d1; break;
    case 2: in = s2; out = d2; break;
    default: in = s3; out = d3; break;
  }
  const int i = blockIdx.x * 256 + threadIdx.x;
  float4 v = ((const float4*)in)[i];
  ushort4 o;
  o.x = f2bf(v.x); o.y = f2bf(v.y); o.z = f2bf(v.z); o.w = f2bf(v.w);
  ((ushort4*)out)[i] = o;
}

extern "C" void kernel_launch(void* const* d_in, const int* in_sizes, int n_in,
                              void* d_out, int out_size, void* d_ws, size_t ws_size,
                              hipStream_t stream)
{
  const float* shape_map = (const float*)d_in[0];
  const float* img_map   = (const float*)d_in[1];
  const float* wq = (const float*)d_in[2];
  const float* bq = (const float*)d_in[3];
  const float* wk = (const float*)d_in[4];
  const float* bk = (const float*)d_in[5];
  const float* wv = (const float*)d_in[6];
  const float* bv = (const float*)d_in[7];
  const float* wc = (const float*)d_in[8];
  const float* bc = (const float*)d_in[9];
  float* out = (float*)d_out;

  const size_t ELT = 1024 * 1024;
  const size_t MB  = 1024 * 1024;
  char* ws = (char*)d_ws;

  // 8MB bf16 weights, then per-batch 10MB slots with buffer reuse:
  //   +0MB: Xt(2)|Yt(2) -> later S fp32(4); +4MB Q->Wsm; +6MB K2->NVt; +8MB Vt
  unsigned short* wq_b = (unsigned short*)(ws + 0 * 2 * MB);
  unsigned short* wk_b = (unsigned short*)(ws + 1 * 2 * MB);
  unsigned short* wv_b = (unsigned short*)(ws + 2 * 2 * MB);
  unsigned short* wc_b = (unsigned short*)(ws + 3 * 2 * MB);
  char* slots = ws + 8 * MB;
  const size_t slotBytes = 10 * MB;
  int nslots = (ws_size > 8 * MB + slotBytes)
                   ? (int)((ws_size - 8 * MB) / slotBytes) : 1;
  if (nslots > 32) nslots = 32;
  if (nslots < 1)  nslots = 1;

  cvt_all<<<dim3(1024, 4), 256, 0, stream>>>(wq, wk, wv, wc,
                                             wq_b, wk_b, wv_b, wc_b);

  const size_t sBf = slotBytes / 2;
  const size_t sF  = slotBytes / 4;

  for (int c0 = 0; c0 < 32; c0 += nslots) {
    const int nb = (32 - c0 < nslots) ? (32 - c0) : nslots;

    unsigned short* Xt  = (unsigned short*)(slots + 0);
    unsigned short* Yt  = (unsigned short*)(slots + 2 * MB);
    float*          Sm  = (float*)(slots + 0);
    unsigned short* Qb  = (unsigned short*)(slots + 4 * MB);
    unsigned short* Kb  = (unsigned short*)(slots + 6 * MB);
    unsigned short* Vt  = (unsigned short*)(slots + 8 * MB);
    unsigned short* Wsm = Qb;   // Q dead after scores
    unsigned short* NVt = Kb;   // K2 dead after scores

    transpose2<<<dim3(32, 32, 2 * nb), dim3(32, 8), 0, stream>>>(
        shape_map + (size_t)c0 * ELT, img_map + (size_t)c0 * ELT,
        Xt, Yt, ELT, sBf, nb);

    // Q[o][s], K2[d][s], Vt[s][d] in one dispatch
    qkv_gemm<<<dim3(4, 4, 3 * nb), 512, 0, stream>>>(
        wq_b, wk_b, wv_b, Xt, Yt, Qb, Kb, Vt, bq, bk, bv, sBf, nb);

    // S[c][d] = Q.K2 / 32   (fp32)
    gemm_bt<1, 0, 0, 0><<<dim3(4, 4, nb), 512, 0, stream>>>(
        Qb, Kb, Sm, nullptr, nullptr, 0.03125f, sBf, sBf, sF, 0);

    softmax_rows<<<dim3(1024, nb), 256, 0, stream>>>(Sm, Wsm, sF, sBf);

    // NVt[s][c] = Vt.Wsm
    gemm_bt<0, 0, 0, 0><<<dim3(4, 4, nb), 512, 0, stream>>>(
        Vt, Wsm, NVt, nullptr, nullptr, 1.0f, sBf, sBf, sBf, 0);

    // out[o][s] = Wc.NVt + bc + shape_map
    gemm_bt<1, 1, 0, 1><<<dim3(4, 4, nb), 512, 0, stream>>>(
        wc_b, NVt, out + (size_t)c0 * ELT, bc,
        shape_map + (size_t)c0 * ELT, 1.0f, 0, sBf, ELT, ELT);
  }
}